// Round 2
// baseline (174.640 us; speedup 1.0000x reference)
//
#include <hip/hip_runtime.h>

// ETNN layer, N=50000 cells, HID=64, DEG=16 neighbors, 4 nodes/cell, sp=3.
// prep: centroids + fp32->bf16 features + positions passthrough
// msg : per-cell [16 nbr x 128] @ W1 (+geom rank-1), silu, @ W2, mean -> msg
// upd : per-16-cell tile [feat|msg] @ Wu1, silu, @ Wu2, residual
//
// MFMA layouts (HW-verified, m89/m91/m120):
//   A[m=lane&15][k=quad*8+j], B[k=quad*8+j][n=lane&15],
//   D[row=quad*4+reg][col=lane&15].
// Layer 1 is computed transposed (D1 = W^T x X^T) with weight frags in
// registers; X fragments load DIRECTLY from global (no LDS staging).
// Hidden round-trips through LDS (absolute row-major) with __syncthreads()
// on both sides of the write phase (compiler + HW memory fence).

#define DEG 16

typedef __attribute__((ext_vector_type(8))) short short8;   // 8 bf16
typedef __attribute__((ext_vector_type(4))) float f32x4;    // MFMA acc

__device__ __forceinline__ unsigned f2bf(float f) {
  unsigned u = __float_as_uint(f);
  return (u + 0x7FFFu + ((u >> 16) & 1u)) >> 16;   // RNE fp32->bf16
}

__device__ __forceinline__ float silu(float h) {
  return h / (1.f + __expf(-h));
}

// ---------------------------------------------------------------- prep ----
__global__ __launch_bounds__(256) void prep_kernel(
    const float* __restrict__ feat, const float* __restrict__ pos,
    unsigned short* __restrict__ featb, float* __restrict__ cent4,
    float* __restrict__ outpos)
{
  int t = blockIdx.x * 256 + threadIdx.x;
  if (t < 800000) {
    const float4 v = ((const float4*)feat)[t];
    ushort4 b;
    b.x = (unsigned short)f2bf(v.x);
    b.y = (unsigned short)f2bf(v.y);
    b.z = (unsigned short)f2bf(v.z);
    b.w = (unsigned short)f2bf(v.w);
    ((ushort4*)featb)[t] = b;
  } else if (t < 950000) {
    const int p = t - 800000;
    ((float4*)outpos)[p] = ((const float4*)pos)[p];
  } else if (t < 1000000) {
    const int i = t - 950000;
    const float4* pp = (const float4*)(pos + 12 * i);   // 48B-aligned
    const float4 a = pp[0], b = pp[1], c = pp[2];
    float4 o;
    o.x = (a.x + a.w + b.z + c.y) * 0.25f;
    o.y = (a.y + b.x + b.w + c.z) * 0.25f;
    o.z = (a.z + b.y + c.x + c.w) * 0.25f;
    o.w = 0.f;
    ((float4*)cent4)[i] = o;
  }
}

// ----------------------------------------------------------------- msg ----
__global__ __launch_bounds__(256) void msg_kernel(
    const unsigned short* __restrict__ featb,
    const float4* __restrict__ cent4,
    const int* __restrict__ nbr,
    const float* __restrict__ W1, const float* __restrict__ b1,
    const float* __restrict__ W2, const float* __restrict__ b2,
    unsigned short* __restrict__ msgb)
{
  __shared__ uint4 HbAll[4 * 144];   // per wave: 16 rows x 144 B
  const int lane = threadIdx.x & 63;
  const int wid  = threadIdx.x >> 6;
  const int quad = lane >> 4;
  const int l15  = lane & 15;
  char* Hb = (char*)(HbAll + wid * 144);

  // --- weight fragments in registers (loaded once per wave) ---
  short8 w1f[4][4];   // A-frags of W1^T: m=mt*16+l15, k=kk*32+quad*8+j
  #pragma unroll
  for (int mt = 0; mt < 4; ++mt)
    #pragma unroll
    for (int kk = 0; kk < 4; ++kk)
      #pragma unroll
      for (int j = 0; j < 8; ++j) {
        const int k = kk * 32 + quad * 8 + j;
        w1f[mt][kk][j] = (short)f2bf(W1[k * 64 + mt * 16 + l15]);
      }
  short8 w2f[4][2];   // B-frags of W2: n=nt*16+l15, k=kk*32+quad*8+j
  #pragma unroll
  for (int nt = 0; nt < 4; ++nt)
    #pragma unroll
    for (int kk = 0; kk < 2; ++kk)
      #pragma unroll
      for (int j = 0; j < 8; ++j) {
        const int k = kk * 32 + quad * 8 + j;
        w2f[nt][kk][j] = (short)f2bf(W2[k * 64 + nt * 16 + l15]);
      }
  f32x4 b1f[4], w1lf[4];
  #pragma unroll
  for (int mt = 0; mt < 4; ++mt) {
    b1f[mt]  = *(const f32x4*)(b1 + mt * 16 + quad * 4);
    w1lf[mt] = *(const f32x4*)(W1 + 8192 + mt * 16 + quad * 4); // geom row 128
  }
  float b2v[4];
  #pragma unroll
  for (int nt = 0; nt < 4; ++nt) b2v[nt] = b2[nt * 16 + l15];

  // uniform trip count per block: c0 is block-wide, cell = c0 + wid < 50000
  // always holds because 50000 % 4 == 0.
  for (int c0 = blockIdx.x * 4; c0 < 50000; c0 += gridDim.x * 4) {
    const int cell = c0 + wid;

    int nj = 0; float g = 0.f;
    if (lane < 16) {
      nj = nbr[cell * DEG + lane];
      const float4 ci = cent4[cell];
      const float4 cj = cent4[nj];
      const float dx = ci.x - cj.x, dy = ci.y - cj.y, dz = ci.z - cj.z;
      g = sqrtf(dx * dx + dy * dy + dz * dz);
    }
    const float g_r  = __shfl(g, l15);   // geom of row r = lane&15
    const int   nj_r = __shfl(nj, l15);  // neighbor id of row r

    // layer 1: hidden^T = W1^T x X^T; B-frags straight from global:
    //   X[r=l15][k] : k<64 -> f_i (broadcast), k>=64 -> f_j (gather)
    f32x4 acc[4] = {};
    #pragma unroll
    for (int kk = 0; kk < 4; ++kk) {
      const unsigned short* src = (kk < 2)
          ? featb + cell * 64 + kk * 32 + quad * 8
          : featb + nj_r * 64 + (kk - 2) * 32 + quad * 8;
      const short8 bf = *(const short8*)src;
      #pragma unroll
      for (int mt = 0; mt < 4; ++mt)
        acc[mt] = __builtin_amdgcn_mfma_f32_16x16x32_bf16(w1f[mt][kk], bf, acc[mt], 0, 0, 0);
    }

    __syncthreads();   // prev iteration's Hb reads complete before overwrite

    // epilogue: +b1 +geom*W1[128], silu, pack 4 consecutive cols
    #pragma unroll
    for (int mt = 0; mt < 4; ++mt) {
      float sv[4];
      #pragma unroll
      for (int rg = 0; rg < 4; ++rg) {
        const float h = acc[mt][rg] + b1f[mt][rg] + g_r * w1lf[mt][rg];
        sv[rg] = silu(h);
      }
      uint2 pk;
      pk.x = f2bf(sv[0]) | (f2bf(sv[1]) << 16);
      pk.y = f2bf(sv[2]) | (f2bf(sv[3]) << 16);
      *(uint2*)(Hb + l15 * 144 + mt * 32 + quad * 8) = pk;
    }

    __syncthreads();   // Hb writes ordered before layer-2 reads

    // layer 2: h2 = hid x W2
    f32x4 acc2[4] = {};
    #pragma unroll
    for (int kk = 0; kk < 2; ++kk) {
      const short8 af = *(const short8*)(Hb + l15 * 144 + kk * 64 + quad * 16);
      #pragma unroll
      for (int nt = 0; nt < 4; ++nt)
        acc2[nt] = __builtin_amdgcn_mfma_f32_16x16x32_bf16(af, w2f[nt][kk], acc2[nt], 0, 0, 0);
    }

    // mean over 16 neighbors: 4 rows in-lane + cross-quad shfl_xor
    #pragma unroll
    for (int nt = 0; nt < 4; ++nt) {
      float s = acc2[nt][0] + acc2[nt][1] + acc2[nt][2] + acc2[nt][3];
      s += __shfl_xor(s, 16);
      s += __shfl_xor(s, 32);
      const float m = s * 0.0625f + b2v[nt];
      if (lane < 16)
        msgb[cell * 64 + nt * 16 + lane] = (unsigned short)f2bf(m);
    }
  }
}

// ----------------------------------------------------------------- upd ----
__global__ __launch_bounds__(256) void upd_kernel(
    const unsigned short* __restrict__ featb,
    const unsigned short* __restrict__ msgb,
    const float* __restrict__ feat,
    const float* __restrict__ Wu1, const float* __restrict__ bu1,
    const float* __restrict__ Wu2, const float* __restrict__ bu2,
    float* __restrict__ outf)
{
  __shared__ uint4 HbAll[4 * 144];
  const int lane = threadIdx.x & 63;
  const int wid  = threadIdx.x >> 6;
  const int quad = lane >> 4;
  const int l15  = lane & 15;
  char* Hb = (char*)(HbAll + wid * 144);

  short8 wu1f[4][4];
  #pragma unroll
  for (int mt = 0; mt < 4; ++mt)
    #pragma unroll
    for (int kk = 0; kk < 4; ++kk)
      #pragma unroll
      for (int j = 0; j < 8; ++j) {
        const int k = kk * 32 + quad * 8 + j;
        wu1f[mt][kk][j] = (short)f2bf(Wu1[k * 64 + mt * 16 + l15]);
      }
  short8 wu2f[4][2];
  #pragma unroll
  for (int nt = 0; nt < 4; ++nt)
    #pragma unroll
    for (int kk = 0; kk < 2; ++kk)
      #pragma unroll
      for (int j = 0; j < 8; ++j) {
        const int k = kk * 32 + quad * 8 + j;
        wu2f[nt][kk][j] = (short)f2bf(Wu2[k * 64 + nt * 16 + l15]);
      }
  f32x4 bu1f[4];
  #pragma unroll
  for (int mt = 0; mt < 4; ++mt)
    bu1f[mt] = *(const f32x4*)(bu1 + mt * 16 + quad * 4);
  float bu2v[4];
  #pragma unroll
  for (int nt = 0; nt < 4; ++nt) bu2v[nt] = bu2[nt * 16 + l15];

  // 3125 tiles of 16 cells; t0 is block-wide so trip count is uniform per
  // block; tail tiles (3125..3127) masked via act.
  for (int t0 = blockIdx.x * 4; t0 < 3125; t0 += gridDim.x * 4) {
    const int tile = t0 + wid;
    const bool act = (tile < 3125);
    const int  tt  = act ? tile : 3124;
    const int  cr  = tt * 16 + l15;   // cell row for B-frags

    // layer 1: U[r=l15][k] : k<64 -> feat row, k>=64 -> msg row
    f32x4 acc[4] = {};
    #pragma unroll
    for (int kk = 0; kk < 4; ++kk) {
      const unsigned short* src = (kk < 2)
          ? featb + cr * 64 + kk * 32 + quad * 8
          : msgb  + cr * 64 + (kk - 2) * 32 + quad * 8;
      const short8 bf = *(const short8*)src;
      #pragma unroll
      for (int mt = 0; mt < 4; ++mt)
        acc[mt] = __builtin_amdgcn_mfma_f32_16x16x32_bf16(wu1f[mt][kk], bf, acc[mt], 0, 0, 0);
    }

    __syncthreads();

    #pragma unroll
    for (int mt = 0; mt < 4; ++mt) {
      float sv[4];
      #pragma unroll
      for (int rg = 0; rg < 4; ++rg)
        sv[rg] = silu(acc[mt][rg] + bu1f[mt][rg]);
      uint2 pk;
      pk.x = f2bf(sv[0]) | (f2bf(sv[1]) << 16);
      pk.y = f2bf(sv[2]) | (f2bf(sv[3]) << 16);
      *(uint2*)(Hb + l15 * 144 + mt * 32 + quad * 8) = pk;
    }

    __syncthreads();

    f32x4 acc2[4] = {};
    #pragma unroll
    for (int kk = 0; kk < 2; ++kk) {
      const short8 af = *(const short8*)(Hb + l15 * 144 + kk * 64 + quad * 16);
      #pragma unroll
      for (int nt = 0; nt < 4; ++nt)
        acc2[nt] = __builtin_amdgcn_mfma_f32_16x16x32_bf16(af, wu2f[nt][kk], acc2[nt], 0, 0, 0);
    }

    if (act) {
      #pragma unroll
      for (int nt = 0; nt < 4; ++nt)
        #pragma unroll
        for (int rg = 0; rg < 4; ++rg) {
          const int row = tt * 16 + quad * 4 + rg;
          const int col = nt * 16 + l15;
          outf[row * 64 + col] = feat[row * 64 + col] + acc2[nt][rg] + bu2v[nt];
        }
    }
  }
}

// -------------------------------------------------------------- launch ----
extern "C" void kernel_launch(void* const* d_in, const int* in_sizes, int n_in,
                              void* d_out, int out_size, void* d_ws, size_t ws_size,
                              hipStream_t stream)
{
  const float* feat = (const float*)d_in[0];
  const float* pos  = (const float*)d_in[1];
  const int*   nbr  = (const int*)d_in[2];
  const float* W1   = (const float*)d_in[3];
  const float* b1   = (const float*)d_in[4];
  const float* W2   = (const float*)d_in[5];
  const float* b2   = (const float*)d_in[6];
  const float* Wu1  = (const float*)d_in[7];
  const float* bu1  = (const float*)d_in[8];
  const float* Wu2  = (const float*)d_in[9];
  const float* bu2  = (const float*)d_in[10];
  float* out = (float*)d_out;

  // ws: featb bf16 [50000*64] @0 (6.4MB), msgb bf16 @6.4MB, cent4 @12.8MB.
  unsigned short* featb = (unsigned short*)d_ws;
  unsigned short* msgb  = (unsigned short*)((char*)d_ws + 6400000);
  float*          cent4 = (float*)((char*)d_ws + 12800000);

  prep_kernel<<<3907, 256, 0, stream>>>(feat, pos, featb, cent4, out + 3200000);
  msg_kernel<<<512, 256, 0, stream>>>(featb, (const float4*)cent4, nbr,
                                      W1, b1, W2, b2, msgb);
  upd_kernel<<<391, 256, 0, stream>>>(featb, msgb, feat, Wu1, bu1, Wu2, bu2, out);
}